// Round 4
// baseline (258.085 us; speedup 1.0000x reference)
//
#include <hip/hip_runtime.h>
#include <stdint.h>
#include <stddef.h>

#define NN 50000
#define NP 50048            // padded rows (782 * 64) for bf16 ws buffers (MFMA A-frag OOB safe)
#define NE 800000
#define NG 128

#define NBKT 256            // dst buckets
#define NPB 196             // nodes per bucket (196*256 = 50176 >= NN)
#define BCAP 4096           // bucket capacity (mean ~3125 + 17 sigma)
#define TILE_E 1536         // edges per partition workgroup (521 blocks ~ 2/CU)
#define PARTB 521           // ceil(NE / TILE_E)
#define AGB 3125            // agg blocks (3125 * 16 nodes = 50000); one block does ALL chunks
#define TFB 782             // transform blocks (NP/64)

typedef __attribute__((ext_vector_type(8))) short bf16x8;
typedef __attribute__((ext_vector_type(4))) float f32x4;
typedef __attribute__((ext_vector_type(4))) unsigned int u32x4;
typedef unsigned short ushort_t;
typedef unsigned int uint_t;

// float -> bf16 (RNE) and bf16x2 unpack helpers
static __device__ inline ushort_t f2b(float f) {
    union { float f; uint_t u; } v; v.f = f;
    uint_t r = v.u + 0x7FFFu + ((v.u >> 16) & 1u);
    return (ushort_t)(r >> 16);
}
static __device__ inline float blo(uint_t u) {
    union { uint_t u; float f; } v; v.u = u << 16; return v.f;
}
static __device__ inline float bhi(uint_t u) {
    union { uint_t u; float f; } v; v.u = u & 0xFFFF0000u; return v.f;
}

// ---------------- K1: partition (blocks 0..PARTB-1) + zero out + inv_cnt (rest) --------
__launch_bounds__(256) static __global__
void part_zero_kernel(const int* __restrict__ src, const int* __restrict__ dst,
                      int* __restrict__ bucket_cnt, uint_t* __restrict__ part,
                      float* __restrict__ out, const int* __restrict__ batch,
                      float* __restrict__ inv_cnt) {
    __shared__ int hist[NBKT];
    int tid = threadIdx.x;
    if (blockIdx.x < PARTB) {
        // two-pass partition: no per-thread arrays -> no scratch spill (R7)
        hist[tid] = 0;
        __syncthreads();
        int base = blockIdx.x * TILE_E;
        int end = min(base + TILE_E, NE);
        for (int i = base + tid; i < end; i += 256)
            atomicAdd(&hist[dst[i] / NPB], 1);
        __syncthreads();
        int r = atomicAdd(&bucket_cnt[tid], hist[tid]);   // reserve
        __syncthreads();
        hist[tid] = r;                                    // reuse as cursor
        __syncthreads();
        for (int i = base + tid; i < end; i += 256) {
            int s = src[i], d = dst[i];
            int b = d / NPB;
            int dl = d - b * NPB;
            int p = atomicAdd(&hist[b], 1);
            part[b * BCAP + p] = ((uint_t)dl << 16) | (uint_t)s;
        }
    } else {
        int gid = (blockIdx.x - PARTB) * 256 + tid;
        if (gid < NG * 64) out[gid] = 0.f;                // d_out is 0xAA-poisoned
        if (gid < NG) {
            int g = gid;
            int lo = 0, hi = NN;
            while (lo < hi) { int m = (lo + hi) >> 1; if (batch[m] < g) lo = m + 1; else hi = m; }
            int start = lo;
            hi = NN;
            while (lo < hi) { int m = (lo + hi) >> 1; if (batch[m] < g + 1) lo = m + 1; else hi = m; }
            inv_cnt[g] = 1.f / (float)max(lo - start, 1);
        }
    }
}

// ---------------- csr_build body (per-bucket CSR, u16 indices + packed offs|deg) -------
static __device__ void csr_build_body(int b, char* smem, const uint_t* __restrict__ part,
                                      const int* __restrict__ bucket_cnt,
                                      uint_t* __restrict__ od, ushort_t* __restrict__ csr) {
    uint_t* stage = (uint_t*)smem;                       // 16384 B
    ushort_t* cstage = (ushort_t*)(smem + 16384);        // 8192 B
    int* cnt_s = (int*)(smem + 24576);                   // 1024 B
    int* scan_l = (int*)(smem + 25600);                  // 1024 B
    int* cur_l = (int*)(smem + 26624);                   // 1024 B
    int tid = threadIdx.x;
    int bc = bucket_cnt[tid];
    cnt_s[tid] = bc;
    scan_l[tid] = bc;
    __syncthreads();
    for (int off = 1; off < NBKT; off <<= 1) {
        int t = (tid >= off) ? scan_l[tid - off] : 0;
        __syncthreads();
        scan_l[tid] += t;
        __syncthreads();
    }
    int base = scan_l[b] - cnt_s[b];
    int n = cnt_s[b];
    __syncthreads();
    cnt_s[tid] = 0;                           // reuse as deg_l
    __syncthreads();
    for (int i = tid; i < n; i += 256) {
        uint_t e = part[(size_t)b * BCAP + i];
        stage[i] = e;
        atomicAdd(&cnt_s[e >> 16], 1);
    }
    __syncthreads();
    int v = cnt_s[tid];
    scan_l[tid] = v;
    __syncthreads();
    for (int off = 1; off < NBKT; off <<= 1) {
        int t = (tid >= off) ? scan_l[tid - off] : 0;
        __syncthreads();
        scan_l[tid] += t;
        __syncthreads();
    }
    int ex = scan_l[tid] - v;
    scan_l[tid] = ex;
    cur_l[tid] = 0;
    __syncthreads();
    int g = b * NPB + tid;
    // packed descriptor: offs in bits [31:8], deg in bits [7:0]
    if (tid < NPB && g < NN) od[g] = ((uint_t)(base + ex) << 8) | (uint_t)v;
    for (int i = tid; i < n; i += 256) {
        uint_t e = stage[i];
        int dl = e >> 16;
        int p = atomicAdd(&cur_l[dl], 1);
        cstage[scan_l[dl] + p] = (ushort_t)(e & 0xFFFFu);
    }
    __syncthreads();
    for (int i = tid; i < n; i += 256) csr[base + i] = cstage[i];
}

// ---------------- MFMA transform body (chunk-major outputs) ----------------
// FP32_IN: layer 0 reads x (fp32) directly, converts to A-frags in-register.
// Outputs chunk-major: tlc[(c*NN+node)*32+f], c = o>>5, f = o&31.
template <int DOUT, int NT, bool FP32_IN>   // OT = 2*DOUT = NT*16, DIN = 96
static __device__ void transform_body(int bid, char* smem,
                                      const void* __restrict__ hin, const float* __restrict__ Wl,
                                      const float* __restrict__ bias, const float* __restrict__ Wr,
                                      ushort_t* __restrict__ tlc, ushort_t* __restrict__ trc) {
    constexpr int DIN = 96;
    short* w_s = (short*)smem;                // NT*3*64*8 shorts (<= 36864 B)
    int tid = threadIdx.x;
    for (int idx = tid; idx < NT * 3 * 64; idx += 256) {
        int ci = idx >> 6, ln = idx & 63;
        int t = ci / 3, s = ci - 3 * t;
        int o = t * 16 + (ln & 15);
        int c0 = s * 32 + (ln >> 4) * 8;
        const float* wrow = (o < DOUT) ? (Wl + (size_t)o * DIN)
                                       : (Wr + (size_t)(o - DOUT) * DIN);
        float4 v0 = *(const float4*)(wrow + c0);
        float4 v1 = *(const float4*)(wrow + c0 + 4);
        bf16x8 pk;
        pk[0] = (short)f2b(v0.x); pk[1] = (short)f2b(v0.y);
        pk[2] = (short)f2b(v0.z); pk[3] = (short)f2b(v0.w);
        pk[4] = (short)f2b(v1.x); pk[5] = (short)f2b(v1.y);
        pk[6] = (short)f2b(v1.z); pk[7] = (short)f2b(v1.w);
        *(bf16x8*)&w_s[idx * 8] = pk;
    }
    int lane = tid & 63;
    int m0 = bid * 64 + (tid >> 6) * 16;
    int row = m0 + (lane & 15);
    bf16x8 a0, a1, a2;
    if (FP32_IN) {
        const float* xr = (const float*)hin + (size_t)min(row, NN - 1) * DIN + (lane >> 4) * 8;
#pragma unroll
        for (int s = 0; s < 3; s++) {
            float4 v0 = *(const float4*)(xr + s * 32);
            float4 v1 = *(const float4*)(xr + s * 32 + 4);
            bf16x8 pk;
            pk[0] = (short)f2b(v0.x); pk[1] = (short)f2b(v0.y);
            pk[2] = (short)f2b(v0.z); pk[3] = (short)f2b(v0.w);
            pk[4] = (short)f2b(v1.x); pk[5] = (short)f2b(v1.y);
            pk[6] = (short)f2b(v1.z); pk[7] = (short)f2b(v1.w);
            if (s == 0) a0 = pk; else if (s == 1) a1 = pk; else a2 = pk;
        }
    } else {
        const bf16x8* arow = (const bf16x8*)((const ushort_t*)hin + (size_t)row * DIN) + (lane >> 4);
        a0 = arow[0];
        a1 = arow[4];
        a2 = arow[8];
    }
    __syncthreads();
    const bf16x8* wp = (const bf16x8*)w_s + lane;
    f32x4 acc[NT];
#pragma unroll
    for (int t = 0; t < NT; t++) {
        acc[t] = (f32x4){0.f, 0.f, 0.f, 0.f};
        acc[t] = __builtin_amdgcn_mfma_f32_16x16x32_bf16(a0, wp[(t * 3 + 0) * 64], acc[t], 0, 0, 0);
        acc[t] = __builtin_amdgcn_mfma_f32_16x16x32_bf16(a1, wp[(t * 3 + 1) * 64], acc[t], 0, 0, 0);
        acc[t] = __builtin_amdgcn_mfma_f32_16x16x32_bf16(a2, wp[(t * 3 + 2) * 64], acc[t], 0, 0, 0);
    }
    int quad = lane >> 4, col = lane & 15;
#pragma unroll
    for (int t = 0; t < NT; t++) {
        int o = t * 16 + col;
        bool is_r = (o >= DOUT);
        float bv = is_r ? bias[o - DOUT] : 0.f;
        ushort_t* outp = is_r ? trc : tlc;
        int oo = is_r ? (o - DOUT) : o;
        int cch = oo >> 5, f = oo & 31;
        ushort_t* ob = outp + ((size_t)cch * NN) * 32 + f;
#pragma unroll
        for (int r = 0; r < 4; r++) {
            int node = m0 + quad * 4 + r;
            if (node < NN) ob[(size_t)node * 32] = f2b(acc[t][r] + bv);
        }
    }
}

// ---------------- K2: csr_build (blocks 0..255) + transform layer0 (rest) ----------------
__launch_bounds__(256) static __global__
void csr_tf0_kernel(const uint_t* __restrict__ part, const int* __restrict__ bucket_cnt,
                    uint_t* __restrict__ od, ushort_t* __restrict__ csr,
                    const float* __restrict__ x, const float* __restrict__ Wl0,
                    const float* __restrict__ b0, const float* __restrict__ Wr0,
                    ushort_t* __restrict__ tlc, ushort_t* __restrict__ trc) {
    __shared__ __align__(16) char smem[36864];
    if (blockIdx.x < NBKT)
        csr_build_body(blockIdx.x, smem, part, bucket_cnt, od, csr);
    else
        transform_body<96, 12, true>(blockIdx.x - NBKT, smem, x, Wl0, b0, Wr0, tlc, trc);
}

// standalone transform (layers 1,2; bf16 input from ws)
template <int DOUT, int NT>
__launch_bounds__(256, 4) static __global__
void transform_kernel(const ushort_t* __restrict__ hb, const float* __restrict__ Wl,
                      const float* __restrict__ bias, const float* __restrict__ Wr,
                      ushort_t* __restrict__ tlc, ushort_t* __restrict__ trc) {
    __shared__ __align__(16) char smem[NT * 3 * 64 * 8 * 2];
    transform_body<DOUT, NT, false>(blockIdx.x, smem, hb, Wl, bias, Wr, tlc, trc);
}

// ---------------- multi-chunk gather inner loop ----------------
// R4: latency-bound (R1/R3 cache tweaks neutral) -> maximize loads-in-flight per
// csr index. One pass gathers ALL NCH chunks: each index fans out to NCH row
// loads (NCH*4 = 12 in flight in the 16-deep tier), csr/od loaded once not NCH x.
template <int NCH>
static __device__ inline void gather_accum_n(const uint_t* __restrict__ tl,
                                             const ushort_t* __restrict__ csr,
                                             int off, int dg, int ng, int fl,
                                             float (&acc)[NCH][8]) {
    constexpr size_t CS = (size_t)NN * 16;   // chunk stride in uints
    int k = 0;
    for (; k + 16 <= dg; k += 16) {
        int s0 = csr[off + k + ng];
        int s1 = csr[off + k + 4 + ng];
        int s2 = csr[off + k + 8 + ng];
        int s3 = csr[off + k + 12 + ng];
#pragma unroll
        for (int c = 0; c < NCH; c++) {
            const uint_t* b = tl + (size_t)c * CS;
            uint4 a0 = *(const uint4*)(b + (size_t)s0 * 16 + 4 * fl);
            uint4 a1 = *(const uint4*)(b + (size_t)s1 * 16 + 4 * fl);
            uint4 a2 = *(const uint4*)(b + (size_t)s2 * 16 + 4 * fl);
            uint4 a3 = *(const uint4*)(b + (size_t)s3 * 16 + 4 * fl);
            acc[c][0] += (blo(a0.x) + blo(a1.x)) + (blo(a2.x) + blo(a3.x));
            acc[c][1] += (bhi(a0.x) + bhi(a1.x)) + (bhi(a2.x) + bhi(a3.x));
            acc[c][2] += (blo(a0.y) + blo(a1.y)) + (blo(a2.y) + blo(a3.y));
            acc[c][3] += (bhi(a0.y) + bhi(a1.y)) + (bhi(a2.y) + bhi(a3.y));
            acc[c][4] += (blo(a0.z) + blo(a1.z)) + (blo(a2.z) + blo(a3.z));
            acc[c][5] += (bhi(a0.z) + bhi(a1.z)) + (bhi(a2.z) + bhi(a3.z));
            acc[c][6] += (blo(a0.w) + blo(a1.w)) + (blo(a2.w) + blo(a3.w));
            acc[c][7] += (bhi(a0.w) + bhi(a1.w)) + (bhi(a2.w) + bhi(a3.w));
        }
    }
    if (k + 8 <= dg) {
        int s0 = csr[off + k + ng];
        int s1 = csr[off + k + 4 + ng];
#pragma unroll
        for (int c = 0; c < NCH; c++) {
            const uint_t* b = tl + (size_t)c * CS;
            uint4 a0 = *(const uint4*)(b + (size_t)s0 * 16 + 4 * fl);
            uint4 a1 = *(const uint4*)(b + (size_t)s1 * 16 + 4 * fl);
            acc[c][0] += blo(a0.x) + blo(a1.x); acc[c][1] += bhi(a0.x) + bhi(a1.x);
            acc[c][2] += blo(a0.y) + blo(a1.y); acc[c][3] += bhi(a0.y) + bhi(a1.y);
            acc[c][4] += blo(a0.z) + blo(a1.z); acc[c][5] += bhi(a0.z) + bhi(a1.z);
            acc[c][6] += blo(a0.w) + blo(a1.w); acc[c][7] += bhi(a0.w) + bhi(a1.w);
        }
        k += 8;
    }
    if (k + 4 <= dg) {
        int s0 = csr[off + k + ng];
#pragma unroll
        for (int c = 0; c < NCH; c++) {
            const uint_t* b = tl + (size_t)c * CS;
            uint4 a0 = *(const uint4*)(b + (size_t)s0 * 16 + 4 * fl);
            acc[c][0] += blo(a0.x); acc[c][1] += bhi(a0.x);
            acc[c][2] += blo(a0.y); acc[c][3] += bhi(a0.y);
            acc[c][4] += blo(a0.z); acc[c][5] += bhi(a0.z);
            acc[c][6] += blo(a0.w); acc[c][7] += bhi(a0.w);
        }
        k += 4;
    }
    if (ng < dg - k) {
        int s0 = csr[off + k + ng];
#pragma unroll
        for (int c = 0; c < NCH; c++) {
            const uint_t* b = tl + (size_t)c * CS;
            uint4 a0 = *(const uint4*)(b + (size_t)s0 * 16 + 4 * fl);
            acc[c][0] += blo(a0.x); acc[c][1] += bhi(a0.x);
            acc[c][2] += blo(a0.y); acc[c][3] += bhi(a0.y);
            acc[c][4] += blo(a0.z); acc[c][5] += bhi(a0.z);
            acc[c][6] += blo(a0.w); acc[c][7] += bhi(a0.w);
        }
    }
}

// ---------------- single-pass aggregation (layers 0,1 -> bf16 next-layer input) -------
// One block = 16 nodes x ALL 3 chunks. Grid AGB (was 3*AGB).
template <int D>
__launch_bounds__(256) static __global__
void agg3_kernel(const ushort_t* __restrict__ tlc, const ushort_t* __restrict__ trc,
                 const uint_t* __restrict__ od, const ushort_t* __restrict__ csr,
                 ushort_t* __restrict__ outb) {
    constexpr int NCH = D / 32;
    constexpr size_t CS = (size_t)NN * 16;
    int b = blockIdx.x;
    int tid = threadIdx.x;
    int node = b * 16 + (tid >> 4);
    int lane = tid & 15;
    int ng = lane >> 2, fl = lane & 3;
    const uint_t* tl = (const uint_t*)tlc;
    uint_t pd = od[node];
    int off = (int)(pd >> 8), dg = (int)(pd & 255u);
    float acc[NCH][8];
#pragma unroll
    for (int c = 0; c < NCH; c++)
#pragma unroll
        for (int q = 0; q < 8; q++) acc[c][q] = 0.f;
    gather_accum_n<NCH>(tl, csr, off, dg, ng, fl, acc);
#pragma unroll
    for (int c = 0; c < NCH; c++)
#pragma unroll
        for (int q = 0; q < 8; q++) {
            acc[c][q] += __shfl_xor(acc[c][q], 4, 64);
            acc[c][q] += __shfl_xor(acc[c][q], 8, 64);
        }
    float s = 1.f / (float)max(dg, 1);
#pragma unroll
    for (int c = 0; c < NCH; c++) {
        u32x4 t = __builtin_nontemporal_load(
            (const u32x4*)((const uint_t*)trc + (size_t)c * CS + (size_t)node * 16 + 4 * fl));
        float v0 = fmaxf(fmaf(acc[c][0], s, blo(t.x)), 0.f);
        float v1 = fmaxf(fmaf(acc[c][1], s, bhi(t.x)), 0.f);
        float v2 = fmaxf(fmaf(acc[c][2], s, blo(t.y)), 0.f);
        float v3 = fmaxf(fmaf(acc[c][3], s, bhi(t.y)), 0.f);
        float v4 = fmaxf(fmaf(acc[c][4], s, blo(t.z)), 0.f);
        float v5 = fmaxf(fmaf(acc[c][5], s, bhi(t.z)), 0.f);
        float v6 = fmaxf(fmaf(acc[c][6], s, blo(t.w)), 0.f);
        float v7 = fmaxf(fmaf(acc[c][7], s, bhi(t.w)), 0.f);
        if (ng == 0) {
            u32x4 o;
            o.x = (uint_t)f2b(v0) | ((uint_t)f2b(v1) << 16);
            o.y = (uint_t)f2b(v2) | ((uint_t)f2b(v3) << 16);
            o.z = (uint_t)f2b(v4) | ((uint_t)f2b(v5) << 16);
            o.w = (uint_t)f2b(v6) | ((uint_t)f2b(v7) << 16);
            __builtin_nontemporal_store(
                o, (u32x4*)((uint_t*)outb + (size_t)node * (D / 2) + c * 16 + 4 * fl));
        }
    }
}

// ---------------- final agg + pool fused (D=64, no relu), pre-divided atomics -------
// Single pass over both chunks; hsum is 16x64 fp32, 64 walkers reduce by graph id.
__launch_bounds__(256) static __global__
void agg_pool_kernel(const ushort_t* __restrict__ tlc, const ushort_t* __restrict__ trc,
                     const uint_t* __restrict__ od, const ushort_t* __restrict__ csr,
                     const int* __restrict__ batch,
                     const float* __restrict__ inv_cnt, float* __restrict__ out) {
    constexpr int NCH = 2;
    constexpr size_t CS = (size_t)NN * 16;
    __shared__ float hsum[16][64];
    __shared__ int gids[16];
    int b = blockIdx.x;
    int tid = threadIdx.x;
    int nl = tid >> 4;
    int node = b * 16 + nl;
    int lane = tid & 15;
    int ng = lane >> 2, fl = lane & 3;
    if (tid < 16) gids[tid] = batch[b * 16 + tid];
    const uint_t* tl = (const uint_t*)tlc;
    uint_t pd = od[node];
    int off = (int)(pd >> 8), dg = (int)(pd & 255u);
    float acc[NCH][8];
#pragma unroll
    for (int c = 0; c < NCH; c++)
#pragma unroll
        for (int q = 0; q < 8; q++) acc[c][q] = 0.f;
    gather_accum_n<NCH>(tl, csr, off, dg, ng, fl, acc);
#pragma unroll
    for (int c = 0; c < NCH; c++)
#pragma unroll
        for (int q = 0; q < 8; q++) {
            acc[c][q] += __shfl_xor(acc[c][q], 4, 64);
            acc[c][q] += __shfl_xor(acc[c][q], 8, 64);
        }
    float s = 1.f / (float)max(dg, 1);
#pragma unroll
    for (int c = 0; c < NCH; c++) {
        u32x4 t = __builtin_nontemporal_load(
            (const u32x4*)((const uint_t*)trc + (size_t)c * CS + (size_t)node * 16 + 4 * fl));
        if (ng == 0) {
            hsum[nl][c * 32 + 8 * fl + 0] = fmaf(acc[c][0], s, blo(t.x));
            hsum[nl][c * 32 + 8 * fl + 1] = fmaf(acc[c][1], s, bhi(t.x));
            hsum[nl][c * 32 + 8 * fl + 2] = fmaf(acc[c][2], s, blo(t.y));
            hsum[nl][c * 32 + 8 * fl + 3] = fmaf(acc[c][3], s, bhi(t.y));
            hsum[nl][c * 32 + 8 * fl + 4] = fmaf(acc[c][4], s, blo(t.z));
            hsum[nl][c * 32 + 8 * fl + 5] = fmaf(acc[c][5], s, bhi(t.z));
            hsum[nl][c * 32 + 8 * fl + 6] = fmaf(acc[c][6], s, blo(t.w));
            hsum[nl][c * 32 + 8 * fl + 7] = fmaf(acc[c][7], s, bhi(t.w));
        }
    }
    __syncthreads();
    if (tid < 64) {
        int gcur = gids[0];
        float ps = 0.f;
        for (int j = 0; j < 16; j++) {
            int g = gids[j];
            if (g != gcur) {
                atomicAdd(&out[gcur * 64 + tid], ps * inv_cnt[gcur]);
                ps = 0.f; gcur = g;
            }
            ps += hsum[j][tid];
        }
        atomicAdd(&out[gcur * 64 + tid], ps * inv_cnt[gcur]);
    }
}

// ---------------- launch ----------------
extern "C" void kernel_launch(void* const* d_in, const int* in_sizes, int n_in,
                              void* d_out, int out_size, void* d_ws, size_t ws_size,
                              hipStream_t stream) {
    (void)in_sizes; (void)n_in; (void)out_size; (void)ws_size;
    const float* x   = (const float*)d_in[0];
    const int*   ei  = (const int*)d_in[1];
    const int*   bat = (const int*)d_in[2];
    const float* Wl0 = (const float*)d_in[3];
    const float* b0  = (const float*)d_in[4];
    const float* Wr0 = (const float*)d_in[5];
    const float* Wl1 = (const float*)d_in[6];
    const float* b1  = (const float*)d_in[7];
    const float* Wr1 = (const float*)d_in[8];
    const float* Wl2 = (const float*)d_in[9];
    const float* b2  = (const float*)d_in[10];
    const float* Wr2 = (const float*)d_in[11];
    float* out = (float*)d_out;
    const int* src = ei;
    const int* dst = ei + NE;

    char* p = (char*)d_ws;
    auto carve = [&](size_t bytes) -> char* {
        char* r = p;
        p += (bytes + 255) & ~(size_t)255;
        return r;
    };
    uint_t*   od     = (uint_t*)carve((size_t)NN * 4);          // packed offs<<8 | deg
    int*      bucket_cnt = (int*)carve(NBKT * 4);
    float*    inv_cnt = (float*)carve(NG * 4);
    uint_t*   part   = (uint_t*)carve((size_t)NBKT * BCAP * 4);
    ushort_t* csr    = (ushort_t*)carve((size_t)NE * 2);        // u16 src indices
    ushort_t* h1b    = (ushort_t*)carve((size_t)NP * 96 * 2);   // layer-1 input
    ushort_t* h2b    = (ushort_t*)carve((size_t)NP * 96 * 2);   // layer-2 input
    ushort_t* tlc    = (ushort_t*)carve((size_t)3 * NN * 32 * 2);  // chunk-major
    ushort_t* trc    = (ushort_t*)carve((size_t)3 * NN * 32 * 2);  // chunk-major

    dim3 b256(256);
    hipMemsetAsync(bucket_cnt, 0, NBKT * 4, stream);

    part_zero_kernel<<<dim3(PARTB + 32), b256, 0, stream>>>(src, dst, bucket_cnt, part,
                                                            out, bat, inv_cnt);
    csr_tf0_kernel<<<dim3(NBKT + TFB), b256, 0, stream>>>(part, bucket_cnt, od, csr,
                                                          x, Wl0, b0, Wr0, tlc, trc);
    agg3_kernel<96><<<dim3(AGB), b256, 0, stream>>>(tlc, trc, od, csr, h1b);
    transform_kernel<96, 12><<<dim3(TFB), b256, 0, stream>>>(h1b, Wl1, b1, Wr1, tlc, trc);
    agg3_kernel<96><<<dim3(AGB), b256, 0, stream>>>(tlc, trc, od, csr, h2b);
    transform_kernel<64, 8><<<dim3(TFB), b256, 0, stream>>>(h2b, Wl2, b2, Wr2, tlc, trc);
    agg_pool_kernel<<<dim3(AGB), b256, 0, stream>>>(tlc, trc, od, csr, bat,
                                                    inv_cnt, out);
}

// Round 5
// 241.309 us; speedup vs baseline: 1.0695x; 1.0695x over previous
//
#include <hip/hip_runtime.h>
#include <stdint.h>
#include <stddef.h>

#define NN 50000
#define NNR 50008           // padded rows per chunk (row NN = zero row for slot padding)
#define NP 50048            // padded rows (782 * 64) for bf16 ws buffers (MFMA A-frag OOB safe)
#define NE 800000
#define NG 128

#define NBKT 256            // dst buckets
#define NPB 196             // nodes per bucket (196*256 = 50176 >= NN)
#define BCAP 4096           // bucket capacity (mean ~3125 + 17 sigma)
#define TILE_E 1536         // edges per partition workgroup (521 blocks ~ 2/CU)
#define PARTB 521           // ceil(NE / TILE_E)
#define AGB2 1563           // agg blocks per chunk (1563 * 32 nodes >= 50000)
#define TFB 782             // transform blocks (NP/64)
#define ZR NN               // zero-row index (gather padding target)

typedef __attribute__((ext_vector_type(8))) short bf16x8;
typedef __attribute__((ext_vector_type(4))) float f32x4;
typedef __attribute__((ext_vector_type(4))) unsigned int u32x4;
typedef unsigned short ushort_t;
typedef unsigned int uint_t;

#define CS_U ((size_t)NNR * 16)   // chunk stride in uints (NNR rows x 64B)

// float -> bf16 (RNE) and bf16x2 unpack helpers
static __device__ inline ushort_t f2b(float f) {
    union { float f; uint_t u; } v; v.f = f;
    uint_t r = v.u + 0x7FFFu + ((v.u >> 16) & 1u);
    return (ushort_t)(r >> 16);
}
static __device__ inline float blo(uint_t u) {
    union { uint_t u; float f; } v; v.u = u << 16; return v.f;
}
static __device__ inline float bhi(uint_t u) {
    union { uint_t u; float f; } v; v.u = u & 0xFFFF0000u; return v.f;
}

// ---------------- K1: partition (blocks 0..PARTB-1) + zero out/pad + inv_cnt (rest) ----
__launch_bounds__(256) static __global__
void part_zero_kernel(const int* __restrict__ src, const int* __restrict__ dst,
                      int* __restrict__ bucket_cnt, uint_t* __restrict__ part,
                      float* __restrict__ out, const int* __restrict__ batch,
                      float* __restrict__ inv_cnt, uint_t* __restrict__ tlz) {
    __shared__ int hist[NBKT];
    int tid = threadIdx.x;
    if (blockIdx.x < PARTB) {
        // two-pass partition: no per-thread arrays -> no scratch spill (R7)
        hist[tid] = 0;
        __syncthreads();
        int base = blockIdx.x * TILE_E;
        int end = min(base + TILE_E, NE);
        for (int i = base + tid; i < end; i += 256)
            atomicAdd(&hist[dst[i] / NPB], 1);
        __syncthreads();
        int r = atomicAdd(&bucket_cnt[tid], hist[tid]);   // reserve
        __syncthreads();
        hist[tid] = r;                                    // reuse as cursor
        __syncthreads();
        for (int i = base + tid; i < end; i += 256) {
            int s = src[i], d = dst[i];
            int b = d / NPB;
            int dl = d - b * NPB;
            int p = atomicAdd(&hist[b], 1);
            part[b * BCAP + p] = ((uint_t)dl << 16) | (uint_t)s;
        }
    } else {
        int gid = (blockIdx.x - PARTB) * 256 + tid;
        if (gid < NG * 64) out[gid] = 0.f;                // d_out is 0xAA-poisoned
        if (gid < 48) {                                   // zero-row of each tl chunk
            int cc = gid >> 4, ii = gid & 15;
            tlz[(size_t)cc * CS_U + (size_t)ZR * 16 + ii] = 0u;
        }
        if (gid < NG) {
            int g = gid;
            int lo = 0, hi = NN;
            while (lo < hi) { int m = (lo + hi) >> 1; if (batch[m] < g) lo = m + 1; else hi = m; }
            int start = lo;
            hi = NN;
            while (lo < hi) { int m = (lo + hi) >> 1; if (batch[m] < g + 1) lo = m + 1; else hi = m; }
            inv_cnt[g] = 1.f / (float)max(lo - start, 1);
        }
    }
}

// ---------------- csr_build body (per-bucket CSR, u16 indices + packed offs|deg) -------
static __device__ void csr_build_body(int b, char* smem, const uint_t* __restrict__ part,
                                      const int* __restrict__ bucket_cnt,
                                      uint_t* __restrict__ od, ushort_t* __restrict__ csr) {
    uint_t* stage = (uint_t*)smem;                       // 16384 B
    ushort_t* cstage = (ushort_t*)(smem + 16384);        // 8192 B
    int* cnt_s = (int*)(smem + 24576);                   // 1024 B
    int* scan_l = (int*)(smem + 25600);                  // 1024 B
    int* cur_l = (int*)(smem + 26624);                   // 1024 B
    int tid = threadIdx.x;
    int bc = bucket_cnt[tid];
    cnt_s[tid] = bc;
    scan_l[tid] = bc;
    __syncthreads();
    for (int off = 1; off < NBKT; off <<= 1) {
        int t = (tid >= off) ? scan_l[tid - off] : 0;
        __syncthreads();
        scan_l[tid] += t;
        __syncthreads();
    }
    int base = scan_l[b] - cnt_s[b];
    int n = cnt_s[b];
    __syncthreads();
    cnt_s[tid] = 0;                           // reuse as deg_l
    __syncthreads();
    for (int i = tid; i < n; i += 256) {
        uint_t e = part[(size_t)b * BCAP + i];
        stage[i] = e;
        atomicAdd(&cnt_s[e >> 16], 1);
    }
    __syncthreads();
    int v = cnt_s[tid];
    scan_l[tid] = v;
    __syncthreads();
    for (int off = 1; off < NBKT; off <<= 1) {
        int t = (tid >= off) ? scan_l[tid - off] : 0;
        __syncthreads();
        scan_l[tid] += t;
        __syncthreads();
    }
    int ex = scan_l[tid] - v;
    scan_l[tid] = ex;
    cur_l[tid] = 0;
    __syncthreads();
    int g = b * NPB + tid;
    // packed descriptor: offs in bits [31:8], deg in bits [7:0]
    if (tid < NPB && g < NN) od[g] = ((uint_t)(base + ex) << 8) | (uint_t)v;
    for (int i = tid; i < n; i += 256) {
        uint_t e = stage[i];
        int dl = e >> 16;
        int p = atomicAdd(&cur_l[dl], 1);
        cstage[scan_l[dl] + p] = (ushort_t)(e & 0xFFFFu);
    }
    __syncthreads();
    for (int i = tid; i < n; i += 256) csr[base + i] = cstage[i];
}

// ---------------- MFMA transform body (chunk-major outputs, NNR row stride) ----------
// FP32_IN: layer 0 reads x (fp32) directly, converts to A-frags in-register.
// Outputs chunk-major: tlc[(c*NNR+node)*32+f], c = o>>5, f = o&31.
template <int DOUT, int NT, bool FP32_IN>   // OT = 2*DOUT = NT*16, DIN = 96
static __device__ void transform_body(int bid, char* smem,
                                      const void* __restrict__ hin, const float* __restrict__ Wl,
                                      const float* __restrict__ bias, const float* __restrict__ Wr,
                                      ushort_t* __restrict__ tlc, ushort_t* __restrict__ trc) {
    constexpr int DIN = 96;
    short* w_s = (short*)smem;                // NT*3*64*8 shorts (<= 36864 B)
    int tid = threadIdx.x;
    for (int idx = tid; idx < NT * 3 * 64; idx += 256) {
        int ci = idx >> 6, ln = idx & 63;
        int t = ci / 3, s = ci - 3 * t;
        int o = t * 16 + (ln & 15);
        int c0 = s * 32 + (ln >> 4) * 8;
        const float* wrow = (o < DOUT) ? (Wl + (size_t)o * DIN)
                                       : (Wr + (size_t)(o - DOUT) * DIN);
        float4 v0 = *(const float4*)(wrow + c0);
        float4 v1 = *(const float4*)(wrow + c0 + 4);
        bf16x8 pk;
        pk[0] = (short)f2b(v0.x); pk[1] = (short)f2b(v0.y);
        pk[2] = (short)f2b(v0.z); pk[3] = (short)f2b(v0.w);
        pk[4] = (short)f2b(v1.x); pk[5] = (short)f2b(v1.y);
        pk[6] = (short)f2b(v1.z); pk[7] = (short)f2b(v1.w);
        *(bf16x8*)&w_s[idx * 8] = pk;
    }
    int lane = tid & 63;
    int m0 = bid * 64 + (tid >> 6) * 16;
    int row = m0 + (lane & 15);
    bf16x8 a0, a1, a2;
    if (FP32_IN) {
        const float* xr = (const float*)hin + (size_t)min(row, NN - 1) * DIN + (lane >> 4) * 8;
#pragma unroll
        for (int s = 0; s < 3; s++) {
            float4 v0 = *(const float4*)(xr + s * 32);
            float4 v1 = *(const float4*)(xr + s * 32 + 4);
            bf16x8 pk;
            pk[0] = (short)f2b(v0.x); pk[1] = (short)f2b(v0.y);
            pk[2] = (short)f2b(v0.z); pk[3] = (short)f2b(v0.w);
            pk[4] = (short)f2b(v1.x); pk[5] = (short)f2b(v1.y);
            pk[6] = (short)f2b(v1.z); pk[7] = (short)f2b(v1.w);
            if (s == 0) a0 = pk; else if (s == 1) a1 = pk; else a2 = pk;
        }
    } else {
        const bf16x8* arow = (const bf16x8*)((const ushort_t*)hin + (size_t)row * DIN) + (lane >> 4);
        a0 = arow[0];
        a1 = arow[4];
        a2 = arow[8];
    }
    __syncthreads();
    const bf16x8* wp = (const bf16x8*)w_s + lane;
    f32x4 acc[NT];
#pragma unroll
    for (int t = 0; t < NT; t++) {
        acc[t] = (f32x4){0.f, 0.f, 0.f, 0.f};
        acc[t] = __builtin_amdgcn_mfma_f32_16x16x32_bf16(a0, wp[(t * 3 + 0) * 64], acc[t], 0, 0, 0);
        acc[t] = __builtin_amdgcn_mfma_f32_16x16x32_bf16(a1, wp[(t * 3 + 1) * 64], acc[t], 0, 0, 0);
        acc[t] = __builtin_amdgcn_mfma_f32_16x16x32_bf16(a2, wp[(t * 3 + 2) * 64], acc[t], 0, 0, 0);
    }
    int quad = lane >> 4, col = lane & 15;
#pragma unroll
    for (int t = 0; t < NT; t++) {
        int o = t * 16 + col;
        bool is_r = (o >= DOUT);
        float bv = is_r ? bias[o - DOUT] : 0.f;
        ushort_t* outp = is_r ? trc : tlc;
        int oo = is_r ? (o - DOUT) : o;
        int cch = oo >> 5, f = oo & 31;
        ushort_t* ob = outp + ((size_t)cch * NNR) * 32 + f;
#pragma unroll
        for (int r = 0; r < 4; r++) {
            int node = m0 + quad * 4 + r;
            if (node < NN) ob[(size_t)node * 32] = f2b(acc[t][r] + bv);
        }
    }
}

// ---------------- K2: csr_build (blocks 0..255) + transform layer0 (rest) ----------------
__launch_bounds__(256) static __global__
void csr_tf0_kernel(const uint_t* __restrict__ part, const int* __restrict__ bucket_cnt,
                    uint_t* __restrict__ od, ushort_t* __restrict__ csr,
                    const float* __restrict__ x, const float* __restrict__ Wl0,
                    const float* __restrict__ b0, const float* __restrict__ Wr0,
                    ushort_t* __restrict__ tlc, ushort_t* __restrict__ trc) {
    __shared__ __align__(16) char smem[36864];
    if (blockIdx.x < NBKT)
        csr_build_body(blockIdx.x, smem, part, bucket_cnt, od, csr);
    else
        transform_body<96, 12, true>(blockIdx.x - NBKT, smem, x, Wl0, b0, Wr0, tlc, trc);
}

// standalone transform (layers 1,2; bf16 input from ws)
template <int DOUT, int NT>
__launch_bounds__(256, 4) static __global__
void transform_kernel(const ushort_t* __restrict__ hb, const float* __restrict__ Wl,
                      const float* __restrict__ bias, const float* __restrict__ Wr,
                      ushort_t* __restrict__ tlc, ushort_t* __restrict__ trc) {
    __shared__ __align__(16) char smem[NT * 3 * 64 * 8 * 2];
    transform_body<DOUT, NT, false>(blockIdx.x, smem, hb, Wl, bias, Wr, tlc, trc);
}

// ---------------- paired-node gather (R5) ----------------
// Latency-bound on L2 hits (R4: blowing L2 hurt; R1/R3: byte cuts neutral).
// Two nodes per 16-lane group -> 8 independent row loads in flight per lane-iter
// (vs 4), SAME 3.2 MB chunk working set. Uniform branch-free loop: invalid slots
// redirect to the zero row ZR (row NN, zeroed in part_zero), killing the tier cascade.
#define ACC4(acc, r0, r1, r2, r3)                                   \
    acc[0] += (blo(r0.x) + blo(r1.x)) + (blo(r2.x) + blo(r3.x));    \
    acc[1] += (bhi(r0.x) + bhi(r1.x)) + (bhi(r2.x) + bhi(r3.x));    \
    acc[2] += (blo(r0.y) + blo(r1.y)) + (blo(r2.y) + blo(r3.y));    \
    acc[3] += (bhi(r0.y) + bhi(r1.y)) + (bhi(r2.y) + bhi(r3.y));    \
    acc[4] += (blo(r0.z) + blo(r1.z)) + (blo(r2.z) + blo(r3.z));    \
    acc[5] += (bhi(r0.z) + bhi(r1.z)) + (bhi(r2.z) + bhi(r3.z));    \
    acc[6] += (blo(r0.w) + blo(r1.w)) + (blo(r2.w) + blo(r3.w));    \
    acc[7] += (bhi(r0.w) + bhi(r1.w)) + (bhi(r2.w) + bhi(r3.w));

static __device__ inline void gather2(const uint_t* __restrict__ tl,
                                      const ushort_t* __restrict__ csr,
                                      int offA, int dgA, int offB, int dgB,
                                      int ng, int fl,
                                      float* __restrict__ accA, float* __restrict__ accB) {
    int kmax = max(dgA, dgB);
    for (int k = 0; k < kmax; k += 16) {
        int sl0 = k + ng, sl1 = k + 4 + ng, sl2 = k + 8 + ng, sl3 = k + 12 + ng;
        // unconditional index loads (reads past a node's list are discarded below;
        // worst case ~508B past csr end stays inside d_ws carves)
        int ia0 = csr[offA + sl0], ia1 = csr[offA + sl1];
        int ia2 = csr[offA + sl2], ia3 = csr[offA + sl3];
        int ib0 = csr[offB + sl0], ib1 = csr[offB + sl1];
        int ib2 = csr[offB + sl2], ib3 = csr[offB + sl3];
        ia0 = sl0 < dgA ? ia0 : ZR;  ia1 = sl1 < dgA ? ia1 : ZR;
        ia2 = sl2 < dgA ? ia2 : ZR;  ia3 = sl3 < dgA ? ia3 : ZR;
        ib0 = sl0 < dgB ? ib0 : ZR;  ib1 = sl1 < dgB ? ib1 : ZR;
        ib2 = sl2 < dgB ? ib2 : ZR;  ib3 = sl3 < dgB ? ib3 : ZR;
        uint4 rA0 = *(const uint4*)(tl + (size_t)ia0 * 16 + 4 * fl);
        uint4 rA1 = *(const uint4*)(tl + (size_t)ia1 * 16 + 4 * fl);
        uint4 rA2 = *(const uint4*)(tl + (size_t)ia2 * 16 + 4 * fl);
        uint4 rA3 = *(const uint4*)(tl + (size_t)ia3 * 16 + 4 * fl);
        uint4 rB0 = *(const uint4*)(tl + (size_t)ib0 * 16 + 4 * fl);
        uint4 rB1 = *(const uint4*)(tl + (size_t)ib1 * 16 + 4 * fl);
        uint4 rB2 = *(const uint4*)(tl + (size_t)ib2 * 16 + 4 * fl);
        uint4 rB3 = *(const uint4*)(tl + (size_t)ib3 * 16 + 4 * fl);
        ACC4(accA, rA0, rA1, rA2, rA3)
        ACC4(accB, rB0, rB1, rB2, rB3)
    }
}

// ---------------- chunked aggregation (layers 0,1 -> bf16 next-layer input) -----------
// One block = 32 nodes (16 pair-groups) x ONE chunk. Grid 3*AGB2.
template <int D>
__launch_bounds__(256) static __global__
void agg3_kernel(const ushort_t* __restrict__ tlc, const ushort_t* __restrict__ trc,
                 const uint_t* __restrict__ od, const ushort_t* __restrict__ csr,
                 ushort_t* __restrict__ outb) {
    int bx = blockIdx.x;
    int c = bx / AGB2;
    int b = bx - c * AGB2;
    int tid = threadIdx.x;
    int g16 = tid >> 4;
    int nodeA = b * 32 + g16 * 2;
    int nodeB = nodeA + 1;
    int lane = tid & 15;
    int ng = lane >> 2, fl = lane & 3;
    const uint_t* tl = (const uint_t*)tlc + (size_t)c * CS_U;
    uint_t pdA = od[min(nodeA, NN - 1)];
    uint_t pdB = od[min(nodeB, NN - 1)];
    int offA = (int)(pdA >> 8), dgA = (nodeA < NN) ? (int)(pdA & 255u) : 0;
    int offB = (int)(pdB >> 8), dgB = (nodeB < NN) ? (int)(pdB & 255u) : 0;
    float accA[8], accB[8];
#pragma unroll
    for (int q = 0; q < 8; q++) { accA[q] = 0.f; accB[q] = 0.f; }
    gather2(tl, csr, offA, dgA, offB, dgB, ng, fl, accA, accB);
#pragma unroll
    for (int q = 0; q < 8; q++) {
        accA[q] += __shfl_xor(accA[q], 4, 64);
        accA[q] += __shfl_xor(accA[q], 8, 64);
        accB[q] += __shfl_xor(accB[q], 4, 64);
        accB[q] += __shfl_xor(accB[q], 8, 64);
    }
    const uint_t* trb = (const uint_t*)trc + (size_t)c * CS_U;
#pragma unroll
    for (int half = 0; half < 2; half++) {
        int node = half ? nodeB : nodeA;
        float* acc = half ? accB : accA;
        int dg = half ? dgB : dgA;
        float s = 1.f / (float)max(dg, 1);
        u32x4 t = __builtin_nontemporal_load(
            (const u32x4*)(trb + (size_t)min(node, NN - 1) * 16 + 4 * fl));
        float v0 = fmaxf(fmaf(acc[0], s, blo(t.x)), 0.f);
        float v1 = fmaxf(fmaf(acc[1], s, bhi(t.x)), 0.f);
        float v2 = fmaxf(fmaf(acc[2], s, blo(t.y)), 0.f);
        float v3 = fmaxf(fmaf(acc[3], s, bhi(t.y)), 0.f);
        float v4 = fmaxf(fmaf(acc[4], s, blo(t.z)), 0.f);
        float v5 = fmaxf(fmaf(acc[5], s, bhi(t.z)), 0.f);
        float v6 = fmaxf(fmaf(acc[6], s, blo(t.w)), 0.f);
        float v7 = fmaxf(fmaf(acc[7], s, bhi(t.w)), 0.f);
        if (ng == 0 && node < NN) {
            u32x4 o;
            o.x = (uint_t)f2b(v0) | ((uint_t)f2b(v1) << 16);
            o.y = (uint_t)f2b(v2) | ((uint_t)f2b(v3) << 16);
            o.z = (uint_t)f2b(v4) | ((uint_t)f2b(v5) << 16);
            o.w = (uint_t)f2b(v6) | ((uint_t)f2b(v7) << 16);
            __builtin_nontemporal_store(
                o, (u32x4*)((uint_t*)outb + (size_t)node * (D / 2) + c * 16 + 4 * fl));
        }
    }
}

// ---------------- final agg + pool fused (D=64, no relu), pre-divided atomics -------
// 32 nodes/block, one chunk per dispatch slice. Stage 32x32 fp32 in LDS, 32 walkers
// run-length reduce by graph id, atomicAdd of ps * inv_cnt[g] straight into d_out.
__launch_bounds__(256) static __global__
void agg_pool_kernel(const ushort_t* __restrict__ tlc, const ushort_t* __restrict__ trc,
                     const uint_t* __restrict__ od, const ushort_t* __restrict__ csr,
                     const int* __restrict__ batch,
                     const float* __restrict__ inv_cnt, float* __restrict__ out) {
    __shared__ float hsum[32][32];
    __shared__ int gids[32];
    int bx = blockIdx.x;
    int c = bx / AGB2;
    int b = bx - c * AGB2;
    int tid = threadIdx.x;
    int g16 = tid >> 4;
    int nodeA = b * 32 + g16 * 2;
    int nodeB = nodeA + 1;
    int lane = tid & 15;
    int ng = lane >> 2, fl = lane & 3;
    if (tid < 32) gids[tid] = batch[min(b * 32 + tid, NN - 1)];
    const uint_t* tl = (const uint_t*)tlc + (size_t)c * CS_U;
    uint_t pdA = od[min(nodeA, NN - 1)];
    uint_t pdB = od[min(nodeB, NN - 1)];
    int offA = (int)(pdA >> 8), dgA = (nodeA < NN) ? (int)(pdA & 255u) : 0;
    int offB = (int)(pdB >> 8), dgB = (nodeB < NN) ? (int)(pdB & 255u) : 0;
    float accA[8], accB[8];
#pragma unroll
    for (int q = 0; q < 8; q++) { accA[q] = 0.f; accB[q] = 0.f; }
    gather2(tl, csr, offA, dgA, offB, dgB, ng, fl, accA, accB);
#pragma unroll
    for (int q = 0; q < 8; q++) {
        accA[q] += __shfl_xor(accA[q], 4, 64);
        accA[q] += __shfl_xor(accA[q], 8, 64);
        accB[q] += __shfl_xor(accB[q], 4, 64);
        accB[q] += __shfl_xor(accB[q], 8, 64);
    }
    const uint_t* trb = (const uint_t*)trc + (size_t)c * CS_U;
#pragma unroll
    for (int half = 0; half < 2; half++) {
        int node = half ? nodeB : nodeA;
        float* acc = half ? accB : accA;
        int dg = half ? dgB : dgA;
        int nl = g16 * 2 + half;
        float s = 1.f / (float)max(dg, 1);
        u32x4 t = __builtin_nontemporal_load(
            (const u32x4*)(trb + (size_t)min(node, NN - 1) * 16 + 4 * fl));
        if (ng == 0) {
            bool v = node < NN;
            hsum[nl][8 * fl + 0] = v ? fmaf(acc[0], s, blo(t.x)) : 0.f;
            hsum[nl][8 * fl + 1] = v ? fmaf(acc[1], s, bhi(t.x)) : 0.f;
            hsum[nl][8 * fl + 2] = v ? fmaf(acc[2], s, blo(t.y)) : 0.f;
            hsum[nl][8 * fl + 3] = v ? fmaf(acc[3], s, bhi(t.y)) : 0.f;
            hsum[nl][8 * fl + 4] = v ? fmaf(acc[4], s, blo(t.z)) : 0.f;
            hsum[nl][8 * fl + 5] = v ? fmaf(acc[5], s, bhi(t.z)) : 0.f;
            hsum[nl][8 * fl + 6] = v ? fmaf(acc[6], s, blo(t.w)) : 0.f;
            hsum[nl][8 * fl + 7] = v ? fmaf(acc[7], s, bhi(t.w)) : 0.f;
        }
    }
    __syncthreads();
    if (tid < 32) {
        int gcur = gids[0];
        float ps = 0.f;
        for (int j = 0; j < 32; j++) {
            int g = gids[j];
            if (g != gcur) {
                atomicAdd(&out[gcur * 64 + c * 32 + tid], ps * inv_cnt[gcur]);
                ps = 0.f; gcur = g;
            }
            ps += hsum[j][tid];
        }
        atomicAdd(&out[gcur * 64 + c * 32 + tid], ps * inv_cnt[gcur]);
    }
}

// ---------------- launch ----------------
extern "C" void kernel_launch(void* const* d_in, const int* in_sizes, int n_in,
                              void* d_out, int out_size, void* d_ws, size_t ws_size,
                              hipStream_t stream) {
    (void)in_sizes; (void)n_in; (void)out_size; (void)ws_size;
    const float* x   = (const float*)d_in[0];
    const int*   ei  = (const int*)d_in[1];
    const int*   bat = (const int*)d_in[2];
    const float* Wl0 = (const float*)d_in[3];
    const float* b0  = (const float*)d_in[4];
    const float* Wr0 = (const float*)d_in[5];
    const float* Wl1 = (const float*)d_in[6];
    const float* b1  = (const float*)d_in[7];
    const float* Wr1 = (const float*)d_in[8];
    const float* Wl2 = (const float*)d_in[9];
    const float* b2  = (const float*)d_in[10];
    const float* Wr2 = (const float*)d_in[11];
    float* out = (float*)d_out;
    const int* src = ei;
    const int* dst = ei + NE;

    char* p = (char*)d_ws;
    auto carve = [&](size_t bytes) -> char* {
        char* r = p;
        p += (bytes + 255) & ~(size_t)255;
        return r;
    };
    uint_t*   od     = (uint_t*)carve((size_t)NN * 4);          // packed offs<<8 | deg
    int*      bucket_cnt = (int*)carve(NBKT * 4);
    float*    inv_cnt = (float*)carve(NG * 4);
    uint_t*   part   = (uint_t*)carve((size_t)NBKT * BCAP * 4);
    ushort_t* csr    = (ushort_t*)carve((size_t)NE * 2);        // u16 src indices
    ushort_t* h1b    = (ushort_t*)carve((size_t)NP * 96 * 2);   // layer-1 input
    ushort_t* h2b    = (ushort_t*)carve((size_t)NP * 96 * 2);   // layer-2 input
    ushort_t* tlc    = (ushort_t*)carve((size_t)3 * NNR * 32 * 2);  // chunk-major (+zero row)
    ushort_t* trc    = (ushort_t*)carve((size_t)3 * NNR * 32 * 2);  // chunk-major

    dim3 b256(256);
    hipMemsetAsync(bucket_cnt, 0, NBKT * 4, stream);

    part_zero_kernel<<<dim3(PARTB + 32), b256, 0, stream>>>(src, dst, bucket_cnt, part,
                                                            out, bat, inv_cnt, (uint_t*)tlc);
    csr_tf0_kernel<<<dim3(NBKT + TFB), b256, 0, stream>>>(part, bucket_cnt, od, csr,
                                                          x, Wl0, b0, Wr0, tlc, trc);
    agg3_kernel<96><<<dim3(3 * AGB2), b256, 0, stream>>>(tlc, trc, od, csr, h1b);
    transform_kernel<96, 12><<<dim3(TFB), b256, 0, stream>>>(h1b, Wl1, b1, Wr1, tlc, trc);
    agg3_kernel<96><<<dim3(3 * AGB2), b256, 0, stream>>>(tlc, trc, od, csr, h2b);
    transform_kernel<64, 8><<<dim3(TFB), b256, 0, stream>>>(h2b, Wl2, b2, Wr2, tlc, trc);
    agg_pool_kernel<<<dim3(2 * AGB2), b256, 0, stream>>>(tlc, trc, od, csr, bat,
                                                         inv_cnt, out);
}